// Round 10
// baseline (169.366 us; speedup 1.0000x reference)
//
#include <hip/hip_runtime.h>
#include <stdint.h>

// BasicAttention: B=4, C=256, IC=128, N=4096, fp32 in/out.
// R17 = R16 resubmitted verbatim (R16 bench was an infra failure: container
// died twice, kernel never ran). attn L2 burst-smoothing:
// (1) phase rotation -- block starts its key loop at (it+ph)&15, ph=(blk>>3)&15
//     (key order irrelevant: fixed-max softmax, sum commutes; zero cost).
// (2) s_setprio(1) around MFMA clusters (T5): pays once waves are desynced
//     (m191 attn +4-7%; R8's failure was fences, not setprio).
// Cross-round data: non-attn = 84+-2us CONSTANT through every proj variant ->
// proj is not the lever. attn 48.5us vs floors: L2 22.3us (768MB @4.3TB/s/XCD),
// MFMA 9.5us, VALU ~11us; idle = lockstep burstiness of 64 blocks/XCD.
// proj = R14 exact. attn body otherwise EXACT R12.
// R13 lesson: register file saturated (oacc 128 AGPR); no live-range extension.
// Micros: exp2-fold scale -> bare v_exp_f32, permlane32_swap, in-place exp.
// ws: qF 2MB | kF 2MB | vF 4MB | wbf(bf16) 256KB.

#define Bn 4
#define Cn 256
#define ICn 128
#define Nn 4096

typedef __attribute__((ext_vector_type(8))) short bf16x8;
typedef __attribute__((ext_vector_type(4))) float f32x4;
typedef __attribute__((ext_vector_type(16))) float f32x16;
typedef __attribute__((ext_vector_type(8))) int i32x8;

#define SCALE1 0x7f7f7f7f  // e8m0 127 (=2^0) in all 4 bytes: scale = 1.0

__device__ __forceinline__ unsigned short f2bf(float f) {
  union { float f; uint32_t u; } v; v.f = f;
  uint32_t r = (v.u + 0x7fffu + ((v.u >> 16) & 1u)) >> 16;
  return (unsigned short)r;
}

__device__ __forceinline__ uint32_t pk4_fp8(float a, float b, float c, float d) {
  int r = 0;
  r = __builtin_amdgcn_cvt_pk_fp8_f32(a, b, r, false);
  r = __builtin_amdgcn_cvt_pk_fp8_f32(c, d, r, true);
  return (uint32_t)r;
}

// wbf frag-major (bf16): [tile(32)][kk(8)][lane(64)][j(8)]; tiles 0-7 Wq, 8-15 Wk, 16-31 Wv.
__global__ __launch_bounds__(256) void cvt_weights(const float* __restrict__ Wq,
                                                   const float* __restrict__ Wk,
                                                   const float* __restrict__ Wv,
                                                   unsigned short* __restrict__ wbf) {
  int t = blockIdx.x * 256 + threadIdx.x;   // 0..16383 = tile*512 + kk*64 + lane
  int tile = t >> 9;
  int kk = (t >> 6) & 7;
  int lane = t & 63;
  const float* W; int row;
  if (tile < 8)       { W = Wq; row = tile * 16 + (lane & 15); }
  else if (tile < 16) { W = Wk; row = (tile - 8) * 16 + (lane & 15); }
  else                { W = Wv; row = (tile - 16) * 16 + (lane & 15); }
  const float* src = W + (size_t)row * Cn + kk * 32 + (lane >> 4) * 8;
  float4 f0 = *(const float4*)src;
  float4 f1 = *(const float4*)(src + 4);
  ushort4 o0, o1;
  o0.x = f2bf(f0.x); o0.y = f2bf(f0.y); o0.z = f2bf(f0.z); o0.w = f2bf(f0.w);
  o1.x = f2bf(f1.x); o1.y = f2bf(f1.y); o1.z = f2bf(f1.z); o1.w = f2bf(f1.w);
  *(ushort4*)(wbf + (size_t)t * 8)     = o0;
  *(ushort4*)(wbf + (size_t)t * 8 + 4) = o1;
}

// qF/kF fp8 x64-frag layout: [b][nt(128)][mf(2)][lane(64)][32B]; lane = l5*32+px31,
//   dword d at mf covers ic = mf*64 + l5*32 + d*4 .. +3 for pixel px.
// vF fp8 x64-frag layout: [b][kb64(64)][ct(8)][lane(64)][32B]; lane = l5*32+ch31,
//   dword d covers keys = l5*32 + d*4 .. +3 (within the 64-key block) for ch.
// wave0: q, wave1: k, waves 2-3: v (8 vtg each).
__global__ __launch_bounds__(256, 2) void proj_kernel(const float* __restrict__ x,
                                                      const unsigned short* __restrict__ wbf,
                                                      const float* __restrict__ bq,
                                                      const float* __restrict__ bk,
                                                      const float* __restrict__ bv,
                                                      uint8_t* __restrict__ qF,
                                                      uint8_t* __restrict__ kF,
                                                      uint8_t* __restrict__ vF) {
  const int b = blockIdx.y;
  const int ntile = blockIdx.x;            // 32-pixel tile
  const int px0 = ntile * 32;
  const int tid = threadIdx.x;
  const int lane = tid & 63;
  const int w = tid >> 6;
  const int c0 = lane & 15, g = lane >> 4;
  // 128^-0.25 * sqrt(log2(e)), folded into BOTH q and k: S comes out in log2
  // domain so attn softmax is a bare v_exp_f32 (2^x).
  const float hscale = 0.3570958292f;

  __shared__ __align__(16) unsigned short xT[32][264];  // [px][c] (16.9 KB)
  __shared__ __align__(16) uint8_t tb[4][4096];         // per-wave store-staging (16 KB)

  #pragma unroll
  for (int t = 0; t < 8; ++t) {            // 8 c-rows x 128B contiguous per wave-instr
    int c = (tid >> 3) + t * 32;
    int i8 = tid & 7;
    float4 f4 = *(const float4*)(x + ((size_t)(b * Cn + c)) * Nn + px0 + i8 * 4);
    xT[i8 * 4 + 0][c] = f2bf(f4.x);
    xT[i8 * 4 + 1][c] = f2bf(f4.y);
    xT[i8 * 4 + 2][c] = f2bf(f4.z);
    xT[i8 * 4 + 3][c] = f2bf(f4.w);
  }
  __syncthreads();

  bf16x8 a[2][8];   // x frags for both 16-px halves
  #pragma unroll
  for (int h = 0; h < 2; ++h)
    #pragma unroll
    for (int kk = 0; kk < 8; ++kk)
      a[h][kk] = *(const bf16x8*)&xT[h * 16 + c0][kk * 32 + g * 8];

  f32x4 zero = {0.f, 0.f, 0.f, 0.f};
  uint8_t* tw = &tb[w][0];

  if (w < 2) {
    // wave0: q (wbf tiles 0-7), wave1: k (tiles 8-15). A = W (m=ic), B = x^T (n=px).
    const int isq = (w == 0);
    const float* bias = isq ? bq : bk;
    uint8_t* dst = isq ? qF : kF;
    #pragma unroll
    for (int otl = 0; otl < 8; ++otl) {
      const int wt = (isq ? 0 : 8) + otl;
      bf16x8 wf[8];
      #pragma unroll
      for (int kk = 0; kk < 8; ++kk)
        wf[kk] = *(const bf16x8*)(wbf + (((size_t)wt * 8 + kk) << 9) + lane * 8);
      float4 bz = *(const float4*)(bias + otl * 16 + g * 4);
      #pragma unroll
      for (int h = 0; h < 2; ++h) {
        f32x4 acc = zero;
        #pragma unroll
        for (int kk = 0; kk < 8; ++kk)
          acc = __builtin_amdgcn_mfma_f32_16x16x32_bf16(wf[kk], a[h][kk], acc, 0, 0, 0);
        // D: row = ic = otl*16 + g*4 + r, col = px = h*16 + c0
        uint32_t d = pk4_fp8((acc[0] + bz.x) * hscale, (acc[1] + bz.y) * hscale,
                             (acc[2] + bz.z) * hscale, (acc[3] + bz.w) * hscale);
        // dword D = ic/4 = otl*4+g in [0,32): mf = D>>4, l5 = (D>>3)&1, d = D&7
        int D = otl * 4 + g;
        int off = ((D >> 4) << 11) + (((((D >> 3) & 1) << 5) + h * 16 + c0) << 5) + ((D & 7) << 2);
        *(uint32_t*)(tw + off) = d;            // ds_write_b32 (cheap scatter)
      }
    }
    // coalesced store-back: flat LDS layout == flat global frag layout
    size_t base = ((size_t)(b * 128 + ntile)) << 12;   // 4096B per (b,ntile)
    #pragma unroll
    for (int r = 0; r < 4; ++r) {
      uint4 v = *(const uint4*)(tw + r * 1024 + lane * 16);
      *(uint4*)(dst + base + r * 1024 + lane * 16) = v;
    }
  } else {
    // waves 2,3: v tiles. A = x (m=px), B = W^T (n=ch).
    #pragma unroll
    for (int oi = 0; oi < 8; ++oi) {
      const int vtg = (w - 2) * 8 + oi;
      bf16x8 wf[8];
      #pragma unroll
      for (int kk = 0; kk < 8; ++kk)
        wf[kk] = *(const bf16x8*)(wbf + (((size_t)(16 + vtg) * 8 + kk) << 9) + lane * 8);
      const float bias = bv[vtg * 16 + c0];
      #pragma unroll
      for (int h = 0; h < 2; ++h) {
        f32x4 acc = zero;
        #pragma unroll
        for (int kk = 0; kk < 8; ++kk)
          acc = __builtin_amdgcn_mfma_f32_16x16x32_bf16(a[h][kk], wf[kk], acc, 0, 0, 0);
        // D: row = key = px0 + h*16 + g*4 + r, col = ch = vtg*16 + c0
        uint32_t d = pk4_fp8(acc[0] + bias, acc[1] + bias, acc[2] + bias, acc[3] + bias);
        // tb: [ct_local(4)][ch31(32)][32B], dword = h*4+g
        int off = (((vtg >> 1) & 3) << 10) + ((((vtg & 1) << 4) + c0) << 5) + ((h * 4 + g) << 2);
        *(uint32_t*)(tw + off) = d;            // ds_write_b32
      }
    }
    // coalesced store-back: 2 rounds x (two 1KB segments per wave-instr)
    const int ctb = (w - 2) * 4;
    size_t base0 = (((size_t)(b * 64 + (ntile >> 1)) * 8 + ctb) << 11)
                 + (size_t)(((ntile & 1) << 5) << 5);      // lane-half select
    #pragma unroll
    for (int r = 0; r < 2; ++r) {
      int ctl = r * 2 + (lane >> 5);
      int li = lane & 31;
      const uint8_t* s = tw + r * 2048 + lane * 32;
      uint4 v0 = *(const uint4*)(s);
      uint4 v1 = *(const uint4*)(s + 16);
      uint8_t* gp = vF + base0 + ((size_t)ctl << 11) + li * 32;
      *(uint4*)(gp) = v0;
      *(uint4*)(gp + 16) = v1;
    }
  }
}

// attn: 512 blocks x 256 thr (4 waves = 4 key-quarters), 32 q-rows/block,
// 16 iters x 64 keys, all-MX x64 MFMAs. R12 body + phase rotation + setprio.
__global__ __launch_bounds__(256, 2) void attn_kernel(const uint8_t* __restrict__ qF,
                                                      const uint8_t* __restrict__ kF,
                                                      const uint8_t* __restrict__ vF,
                                                      const float* __restrict__ x,
                                                      const float* __restrict__ gamma,
                                                      float* __restrict__ out) {
  const int blk = blockIdx.x;
  const int b = (blk & 7) >> 1;                     // 2 XCDs/batch: q+k+v 2MB < 4MB L2
  const int rg = (blk >> 3) | ((blk & 1) << 6);     // 0..127
  const int n0 = rg * 32;
  const int ph = (blk >> 3) & 15;                   // per-block key-loop phase:
  const int tid = threadIdx.x;                      // co-resident blocks (same blk&7)
  const int L = tid & 63;                           // spread bursts over 16 phases
  const int ks = tid >> 6;                          // key quarter
  const int l31 = L & 31, l5 = L >> 5;
  const bool lo = (l5 == 0);

  __shared__ __align__(16) struct SM {
    float obuf[256][33];                            // epilogue O^T combine (33.8 KB)
    float lsum[4][32];
  } sm;

  // Q B-frags (persistent): col = qrow = n0 + l31; qv[mf] = ic mf*64 + l5*32 + 0..31
  i32x8 qv[2];
  {
    const uint8_t* qp = qF + ((size_t)(b * 128 + rg) * 2) * 2048 + L * 32;
    #pragma unroll
    for (int mf = 0; mf < 2; ++mf) {
      union { uint4 u[2]; i32x8 v; } u;
      u.u[0] = *(const uint4*)(qp + mf * 2048);
      u.u[1] = *(const uint4*)(qp + mf * 2048 + 16);
      qv[mf] = u.v;
    }
  }

  f32x16 oacc[8];                                   // O^T: 256 ch x 32 qrows
  #pragma unroll
  for (int ct = 0; ct < 8; ++ct)
    #pragma unroll
    for (int i = 0; i < 16; ++i) oacc[ct][i] = 0.f;
  float lacc = 0.f;

  const uint8_t* kBase = kF + ((size_t)(b * 128) * 2) * 2048 + L * 32;
  const uint8_t* vBase = vF + ((size_t)(b * 64) * 8) * 2048 + L * 32;

  for (int it = 0; it < 16; ++it) {
    const int kb = ks * 16 + ((it + ph) & 15);      // rotated 64-key block (sum commutes)

    // (1) K frags JIT, issued FIRST: QK's vmcnt wait retires these while the
    //     later-issued V loads stay in flight (in-order retirement).
    i32x8 kv[4];                                    // [tile*2 + mf]
    {
      const uint8_t* kp = kBase + (size_t)kb * 8192;
      #pragma unroll
      for (int f = 0; f < 4; ++f) {
        union { uint4 u[2]; i32x8 v; } u;
        u.u[0] = *(const uint4*)(kp + f * 2048);
        u.u[1] = *(const uint4*)(kp + f * 2048 + 16);
        kv[f] = u.v;
      }
    }

    // (2) V dword-half A (keys l5*32 + 0..15 of each ct); half B issued mid-iter
    //     to cap live VGPRs.
    const uint8_t* vp = vBase + (size_t)kb * 16384;
    uint4 vA[8], vB[8];
    #pragma unroll
    for (int ct = 0; ct < 8; ++ct) vA[ct] = *(const uint4*)(vp + ct * 2048);

    // (3) QK tile1 (keys 0-31), K=128 via 2 x64 steps. S^T: col=l31=qrow,
    //     row(reg i) = key = (i&3)+8*(i>>2)+4*l5.
    f32x16 s;
    #pragma unroll
    for (int i = 0; i < 16; ++i) s[i] = 0.f;
    __builtin_amdgcn_s_setprio(1);
    s = __builtin_amdgcn_mfma_scale_f32_32x32x64_f8f6f4(kv[0], qv[0], s, 0, 0, 0, SCALE1, 0, SCALE1);
    s = __builtin_amdgcn_mfma_scale_f32_32x32x64_f8f6f4(kv[1], qv[1], s, 0, 0, 0, SCALE1, 0, SCALE1);
    __builtin_amdgcn_s_setprio(0);
    // exp/pack tile1 now so only one S tile is ever live (VGPR cap)
    #pragma unroll
    for (int i = 0; i < 16; ++i) {
      float r;
      asm("v_exp_f32 %0, %1" : "=v"(r) : "v"(s[i]));
      s[i] = r;
    }
    #pragma unroll
    for (int i = 0; i < 16; ++i) lacc += s[i];
    uint32_t d0 = pk4_fp8(s[0], s[1], s[2], s[3]);      // keys lo:0-3  hi:4-7
    uint32_t d1 = pk4_fp8(s[4], s[5], s[6], s[7]);      // keys lo:8-11 hi:12-15
    uint32_t d2 = pk4_fp8(s[8], s[9], s[10], s[11]);    // keys lo:16-19 hi:20-23
    uint32_t d3 = pk4_fp8(s[12], s[13], s[14], s[15]);  // keys lo:24-27 hi:28-31

    // (4) QK tile2 (keys 32-63)
    #pragma unroll
    for (int i = 0; i < 16; ++i) s[i] = 0.f;
    __builtin_amdgcn_s_setprio(1);
    s = __builtin_amdgcn_mfma_scale_f32_32x32x64_f8f6f4(kv[2], qv[0], s, 0, 0, 0, SCALE1, 0, SCALE1);
    s = __builtin_amdgcn_mfma_scale_f32_32x32x64_f8f6f4(kv[3], qv[1], s, 0, 0, 0, SCALE1, 0, SCALE1);
    __builtin_amdgcn_s_setprio(0);

    // (5) V dword-half B issue (covered by exp-t2 + swaps + PV front)
    #pragma unroll
    for (int ct = 0; ct < 8; ++ct) vB[ct] = *(const uint4*)(vp + ct * 2048 + 16);

    #pragma unroll
    for (int i = 0; i < 16; ++i) {
      float r;
      asm("v_exp_f32 %0, %1" : "=v"(r) : "v"(s[i]));
      s[i] = r;
    }
    #pragma unroll
    for (int i = 0; i < 16; ++i) lacc += s[i];
    uint32_t e0 = pk4_fp8(s[0], s[1], s[2], s[3]);
    uint32_t e1 = pk4_fp8(s[4], s[5], s[6], s[7]);
    uint32_t e2 = pk4_fp8(s[8], s[9], s[10], s[11]);
    uint32_t e3 = pk4_fp8(s[12], s[13], s[14], s[15]);

    // (6) P^T B-frag (K=64): swap(a=e_i, b=d_i) -> lane<32: a=partner d_i, b=own d_i;
    //     lane>=32: a=own e_i, b=partner e_i. K order = w[2i]=b_i, w[2i+1]=a_i
    //     (lo lanes keys 0-31 = tile1, hi lanes keys 32-63 = tile2). No selects.
    union { uint32_t w[8]; i32x8 v; } pf;
    {
      uint32_t a0 = e0, b0 = d0;
      asm("v_permlane32_swap_b32 %0, %1" : "+v"(a0), "+v"(b0));
      pf.w[0] = b0; pf.w[1] = a0;
      uint32_t a1 = e1, b1 = d1;
      asm("v_permlane32_swap_b32 %0, %1" : "+v"(a1), "+v"(b1));
      pf.w[2] = b1; pf.w[3] = a1;
      uint32_t a2 = e2, b2 = d2;
      asm("v_permlane32_swap_b32 %0, %1" : "+v"(a2), "+v"(b2));
      pf.w[4] = b2; pf.w[5] = a2;
      uint32_t a3 = e3, b3 = d3;
      asm("v_permlane32_swap_b32 %0, %1" : "+v"(a3), "+v"(b3));
      pf.w[6] = b3; pf.w[7] = a3;
    }

    // (7) O^T += V·P^T: 8 x64 MFMAs. D layout identical to before (epilogue unchanged).
    __builtin_amdgcn_s_setprio(1);
    #pragma unroll
    for (int ct = 0; ct < 8; ++ct) {
      union { uint4 u[2]; i32x8 v; } va;
      va.u[0] = vA[ct]; va.u[1] = vB[ct];
      oacc[ct] = __builtin_amdgcn_mfma_scale_f32_32x32x64_f8f6f4(va.v, pf.v, oacc[ct], 0, 0, 0, SCALE1, 0, SCALE1);
    }
    __builtin_amdgcn_s_setprio(0);
  }

  // ---- combine 4 key-quarter waves + epilogue
  float lfin = lacc + __shfl_xor(lacc, 32, 64);

  #pragma unroll
  for (int pq = 0; pq < 4; ++pq) {
    __syncthreads();
    if (pq == 0 && lo) sm.lsum[ks][l31] = lfin;
    if (ks == pq) {
      #pragma unroll
      for (int ct = 0; ct < 8; ++ct) {
        #pragma unroll
        for (int i = 0; i < 16; ++i) {
          int ch = ct * 32 + (i & 3) + 8 * (i >> 2) + 4 * l5;
          if (pq == 0) sm.obuf[ch][l31] = oacc[ct][i];
          else         sm.obuf[ch][l31] += oacc[ct][i];
        }
      }
    }
  }
  __syncthreads();

  const int row = tid & 31;
  const float coef = gamma[0] / (sm.lsum[0][row] + sm.lsum[1][row] +
                                 sm.lsum[2][row] + sm.lsum[3][row]);
  #pragma unroll 4
  for (int t = 0; t < 32; ++t) {
    int ch = (tid >> 5) + t * 8;
    size_t off = ((size_t)(b * Cn + ch)) * Nn + n0 + row;
    out[off] = sm.obuf[ch][row] * coef + 2.0f * x[off];
  }
}

extern "C" void kernel_launch(void* const* d_in, const int* in_sizes, int n_in,
                              void* d_out, int out_size, void* d_ws, size_t ws_size,
                              hipStream_t stream) {
  const float* x     = (const float*)d_in[0];
  const float* Wq    = (const float*)d_in[1];
  const float* bq    = (const float*)d_in[2];
  const float* Wk    = (const float*)d_in[3];
  const float* bk    = (const float*)d_in[4];
  const float* Wv    = (const float*)d_in[5];
  const float* bv    = (const float*)d_in[6];
  const float* gamma = (const float*)d_in[7];
  float* out = (float*)d_out;

  uint8_t* qF = (uint8_t*)d_ws;                       // 2 MB fp8 x64-frag-major
  uint8_t* kF = qF + (2u << 20);                      // 2 MB
  uint8_t* vF = kF + (2u << 20);                      // 4 MB
  unsigned short* wbf = (unsigned short*)(vF + (4u << 20));  // 256 KB bf16 frag-major

  hipLaunchKernelGGL(cvt_weights, dim3(64), dim3(256), 0, stream, Wq, Wk, Wv, wbf);
  hipLaunchKernelGGL(proj_kernel, dim3(128, 4), dim3(256), 0, stream,
                     x, wbf, bq, bk, bv, qF, kF, vF);
  hipLaunchKernelGGL(attn_kernel, dim3(512), dim3(256), 0, stream,
                     qF, kF, vF, x, gamma, out);
}

// Round 11
// 129.299 us; speedup vs baseline: 1.3099x; 1.3099x over previous
//
#include <hip/hip_runtime.h>
#include <stdint.h>

// BasicAttention: B=4, C=256, IC=128, N=4096, fp32 in/out.
// R18: clean A/B of the L2 burst-smoothing hypothesis. R17 bundled TWO changes
// (phase rotation + setprio) and spilled (WRITE_SIZE 16->145MB, attn 90us --
// R13's scratch fingerprint; absmax passed so rotation MATH is correct). Prime
// suspect for the spill: setprio pairs acting as sched fences that pin MFMA
// clusters and block load sinking/remat at ~235/256 regs. This round: phase
// rotation ONLY (ks*16 + ((it+ph)&15), ph=(blk>>3)&15; ~2 VALU ops, 0 regs),
// NO setprio, everything else byte-identical to R14 (132.2us best).
// Check order: (1) WRITE_SIZE==16384 (no spill)? (2) attn 40-45us (burst
// theory confirmed) vs ~48.5 (refuted). Spill again => rotation is the culprit,
// revert to R14 permanently.
// Floors (from R12/R14 counters): MFMA 9.5us, VALU ~11us, L2 22.3us/768MB.
// R13 lesson: register file saturated; no live-range extension, no fences.
// Micros: exp2-fold scale -> bare v_exp_f32, permlane32_swap, in-place exp.
// ws: qF 2MB | kF 2MB | vF 4MB | wbf(bf16) 256KB.

#define Bn 4
#define Cn 256
#define ICn 128
#define Nn 4096

typedef __attribute__((ext_vector_type(8))) short bf16x8;
typedef __attribute__((ext_vector_type(4))) float f32x4;
typedef __attribute__((ext_vector_type(16))) float f32x16;
typedef __attribute__((ext_vector_type(8))) int i32x8;

#define SCALE1 0x7f7f7f7f  // e8m0 127 (=2^0) in all 4 bytes: scale = 1.0

__device__ __forceinline__ unsigned short f2bf(float f) {
  union { float f; uint32_t u; } v; v.f = f;
  uint32_t r = (v.u + 0x7fffu + ((v.u >> 16) & 1u)) >> 16;
  return (unsigned short)r;
}

__device__ __forceinline__ uint32_t pk4_fp8(float a, float b, float c, float d) {
  int r = 0;
  r = __builtin_amdgcn_cvt_pk_fp8_f32(a, b, r, false);
  r = __builtin_amdgcn_cvt_pk_fp8_f32(c, d, r, true);
  return (uint32_t)r;
}

// wbf frag-major (bf16): [tile(32)][kk(8)][lane(64)][j(8)]; tiles 0-7 Wq, 8-15 Wk, 16-31 Wv.
__global__ __launch_bounds__(256) void cvt_weights(const float* __restrict__ Wq,
                                                   const float* __restrict__ Wk,
                                                   const float* __restrict__ Wv,
                                                   unsigned short* __restrict__ wbf) {
  int t = blockIdx.x * 256 + threadIdx.x;   // 0..16383 = tile*512 + kk*64 + lane
  int tile = t >> 9;
  int kk = (t >> 6) & 7;
  int lane = t & 63;
  const float* W; int row;
  if (tile < 8)       { W = Wq; row = tile * 16 + (lane & 15); }
  else if (tile < 16) { W = Wk; row = (tile - 8) * 16 + (lane & 15); }
  else                { W = Wv; row = (tile - 16) * 16 + (lane & 15); }
  const float* src = W + (size_t)row * Cn + kk * 32 + (lane >> 4) * 8;
  float4 f0 = *(const float4*)src;
  float4 f1 = *(const float4*)(src + 4);
  ushort4 o0, o1;
  o0.x = f2bf(f0.x); o0.y = f2bf(f0.y); o0.z = f2bf(f0.z); o0.w = f2bf(f0.w);
  o1.x = f2bf(f1.x); o1.y = f2bf(f1.y); o1.z = f2bf(f1.z); o1.w = f2bf(f1.w);
  *(ushort4*)(wbf + (size_t)t * 8)     = o0;
  *(ushort4*)(wbf + (size_t)t * 8 + 4) = o1;
}

// qF/kF fp8 x64-frag layout: [b][nt(128)][mf(2)][lane(64)][32B]; lane = l5*32+px31,
//   dword d at mf covers ic = mf*64 + l5*32 + d*4 .. +3 for pixel px.
// vF fp8 x64-frag layout: [b][kb64(64)][ct(8)][lane(64)][32B]; lane = l5*32+ch31,
//   dword d covers keys = l5*32 + d*4 .. +3 (within the 64-key block) for ch.
// wave0: q, wave1: k, waves 2-3: v (8 vtg each).
__global__ __launch_bounds__(256, 2) void proj_kernel(const float* __restrict__ x,
                                                      const unsigned short* __restrict__ wbf,
                                                      const float* __restrict__ bq,
                                                      const float* __restrict__ bk,
                                                      const float* __restrict__ bv,
                                                      uint8_t* __restrict__ qF,
                                                      uint8_t* __restrict__ kF,
                                                      uint8_t* __restrict__ vF) {
  const int b = blockIdx.y;
  const int ntile = blockIdx.x;            // 32-pixel tile
  const int px0 = ntile * 32;
  const int tid = threadIdx.x;
  const int lane = tid & 63;
  const int w = tid >> 6;
  const int c0 = lane & 15, g = lane >> 4;
  // 128^-0.25 * sqrt(log2(e)), folded into BOTH q and k: S comes out in log2
  // domain so attn softmax is a bare v_exp_f32 (2^x).
  const float hscale = 0.3570958292f;

  __shared__ __align__(16) unsigned short xT[32][264];  // [px][c] (16.9 KB)
  __shared__ __align__(16) uint8_t tb[4][4096];         // per-wave store-staging (16 KB)

  #pragma unroll
  for (int t = 0; t < 8; ++t) {            // 8 c-rows x 128B contiguous per wave-instr
    int c = (tid >> 3) + t * 32;
    int i8 = tid & 7;
    float4 f4 = *(const float4*)(x + ((size_t)(b * Cn + c)) * Nn + px0 + i8 * 4);
    xT[i8 * 4 + 0][c] = f2bf(f4.x);
    xT[i8 * 4 + 1][c] = f2bf(f4.y);
    xT[i8 * 4 + 2][c] = f2bf(f4.z);
    xT[i8 * 4 + 3][c] = f2bf(f4.w);
  }
  __syncthreads();

  bf16x8 a[2][8];   // x frags for both 16-px halves
  #pragma unroll
  for (int h = 0; h < 2; ++h)
    #pragma unroll
    for (int kk = 0; kk < 8; ++kk)
      a[h][kk] = *(const bf16x8*)&xT[h * 16 + c0][kk * 32 + g * 8];

  f32x4 zero = {0.f, 0.f, 0.f, 0.f};
  uint8_t* tw = &tb[w][0];

  if (w < 2) {
    // wave0: q (wbf tiles 0-7), wave1: k (tiles 8-15). A = W (m=ic), B = x^T (n=px).
    const int isq = (w == 0);
    const float* bias = isq ? bq : bk;
    uint8_t* dst = isq ? qF : kF;
    #pragma unroll
    for (int otl = 0; otl < 8; ++otl) {
      const int wt = (isq ? 0 : 8) + otl;
      bf16x8 wf[8];
      #pragma unroll
      for (int kk = 0; kk < 8; ++kk)
        wf[kk] = *(const bf16x8*)(wbf + (((size_t)wt * 8 + kk) << 9) + lane * 8);
      float4 bz = *(const float4*)(bias + otl * 16 + g * 4);
      #pragma unroll
      for (int h = 0; h < 2; ++h) {
        f32x4 acc = zero;
        #pragma unroll
        for (int kk = 0; kk < 8; ++kk)
          acc = __builtin_amdgcn_mfma_f32_16x16x32_bf16(wf[kk], a[h][kk], acc, 0, 0, 0);
        // D: row = ic = otl*16 + g*4 + r, col = px = h*16 + c0
        uint32_t d = pk4_fp8((acc[0] + bz.x) * hscale, (acc[1] + bz.y) * hscale,
                             (acc[2] + bz.z) * hscale, (acc[3] + bz.w) * hscale);
        // dword D = ic/4 = otl*4+g in [0,32): mf = D>>4, l5 = (D>>3)&1, d = D&7
        int D = otl * 4 + g;
        int off = ((D >> 4) << 11) + (((((D >> 3) & 1) << 5) + h * 16 + c0) << 5) + ((D & 7) << 2);
        *(uint32_t*)(tw + off) = d;            // ds_write_b32 (cheap scatter)
      }
    }
    // coalesced store-back: flat LDS layout == flat global frag layout
    size_t base = ((size_t)(b * 128 + ntile)) << 12;   // 4096B per (b,ntile)
    #pragma unroll
    for (int r = 0; r < 4; ++r) {
      uint4 v = *(const uint4*)(tw + r * 1024 + lane * 16);
      *(uint4*)(dst + base + r * 1024 + lane * 16) = v;
    }
  } else {
    // waves 2,3: v tiles. A = x (m=px), B = W^T (n=ch).
    #pragma unroll
    for (int oi = 0; oi < 8; ++oi) {
      const int vtg = (w - 2) * 8 + oi;
      bf16x8 wf[8];
      #pragma unroll
      for (int kk = 0; kk < 8; ++kk)
        wf[kk] = *(const bf16x8*)(wbf + (((size_t)(16 + vtg) * 8 + kk) << 9) + lane * 8);
      const float bias = bv[vtg * 16 + c0];
      #pragma unroll
      for (int h = 0; h < 2; ++h) {
        f32x4 acc = zero;
        #pragma unroll
        for (int kk = 0; kk < 8; ++kk)
          acc = __builtin_amdgcn_mfma_f32_16x16x32_bf16(a[h][kk], wf[kk], acc, 0, 0, 0);
        // D: row = key = px0 + h*16 + g*4 + r, col = ch = vtg*16 + c0
        uint32_t d = pk4_fp8(acc[0] + bias, acc[1] + bias, acc[2] + bias, acc[3] + bias);
        // tb: [ct_local(4)][ch31(32)][32B], dword = h*4+g
        int off = (((vtg >> 1) & 3) << 10) + ((((vtg & 1) << 4) + c0) << 5) + ((h * 4 + g) << 2);
        *(uint32_t*)(tw + off) = d;            // ds_write_b32
      }
    }
    // coalesced store-back: 2 rounds x (two 1KB segments per wave-instr)
    const int ctb = (w - 2) * 4;
    size_t base0 = (((size_t)(b * 64 + (ntile >> 1)) * 8 + ctb) << 11)
                 + (size_t)(((ntile & 1) << 5) << 5);      // lane-half select
    #pragma unroll
    for (int r = 0; r < 2; ++r) {
      int ctl = r * 2 + (lane >> 5);
      int li = lane & 31;
      const uint8_t* s = tw + r * 2048 + lane * 32;
      uint4 v0 = *(const uint4*)(s);
      uint4 v1 = *(const uint4*)(s + 16);
      uint8_t* gp = vF + base0 + ((size_t)ctl << 11) + li * 32;
      *(uint4*)(gp) = v0;
      *(uint4*)(gp + 16) = v1;
    }
  }
}

// attn: 512 blocks x 256 thr (4 waves = 4 key-quarters), 32 q-rows/block,
// 16 iters x 64 keys, all-MX x64 MFMAs. R12 body + phase rotation ONLY.
__global__ __launch_bounds__(256, 2) void attn_kernel(const uint8_t* __restrict__ qF,
                                                      const uint8_t* __restrict__ kF,
                                                      const uint8_t* __restrict__ vF,
                                                      const float* __restrict__ x,
                                                      const float* __restrict__ gamma,
                                                      float* __restrict__ out) {
  const int blk = blockIdx.x;
  const int b = (blk & 7) >> 1;                     // 2 XCDs/batch: q+k+v 2MB < 4MB L2
  const int rg = (blk >> 3) | ((blk & 1) << 6);     // 0..127
  const int n0 = rg * 32;
  const int ph = (blk >> 3) & 15;                   // per-block key-loop phase:
  const int tid = threadIdx.x;                      // co-resident blocks (same blk&7)
  const int L = tid & 63;                           // spread bursts over 16 phases
  const int ks = tid >> 6;                          // key quarter
  const int l31 = L & 31, l5 = L >> 5;
  const bool lo = (l5 == 0);

  __shared__ __align__(16) struct SM {
    float obuf[256][33];                            // epilogue O^T combine (33.8 KB)
    float lsum[4][32];
  } sm;

  // Q B-frags (persistent): col = qrow = n0 + l31; qv[mf] = ic mf*64 + l5*32 + 0..31
  i32x8 qv[2];
  {
    const uint8_t* qp = qF + ((size_t)(b * 128 + rg) * 2) * 2048 + L * 32;
    #pragma unroll
    for (int mf = 0; mf < 2; ++mf) {
      union { uint4 u[2]; i32x8 v; } u;
      u.u[0] = *(const uint4*)(qp + mf * 2048);
      u.u[1] = *(const uint4*)(qp + mf * 2048 + 16);
      qv[mf] = u.v;
    }
  }

  f32x16 oacc[8];                                   // O^T: 256 ch x 32 qrows
  #pragma unroll
  for (int ct = 0; ct < 8; ++ct)
    #pragma unroll
    for (int i = 0; i < 16; ++i) oacc[ct][i] = 0.f;
  float lacc = 0.f;

  const uint8_t* kBase = kF + ((size_t)(b * 128) * 2) * 2048 + L * 32;
  const uint8_t* vBase = vF + ((size_t)(b * 64) * 8) * 2048 + L * 32;

  for (int it = 0; it < 16; ++it) {
    const int kb = ks * 16 + ((it + ph) & 15);      // rotated 64-key block (sum commutes)

    // (1) K frags JIT, issued FIRST: QK's vmcnt wait retires these while the
    //     later-issued V loads stay in flight (in-order retirement).
    i32x8 kv[4];                                    // [tile*2 + mf]
    {
      const uint8_t* kp = kBase + (size_t)kb * 8192;
      #pragma unroll
      for (int f = 0; f < 4; ++f) {
        union { uint4 u[2]; i32x8 v; } u;
        u.u[0] = *(const uint4*)(kp + f * 2048);
        u.u[1] = *(const uint4*)(kp + f * 2048 + 16);
        kv[f] = u.v;
      }
    }

    // (2) V dword-half A (keys l5*32 + 0..15 of each ct); half B issued mid-iter
    //     to cap live VGPRs.
    const uint8_t* vp = vBase + (size_t)kb * 16384;
    uint4 vA[8], vB[8];
    #pragma unroll
    for (int ct = 0; ct < 8; ++ct) vA[ct] = *(const uint4*)(vp + ct * 2048);

    // (3) QK tile1 (keys 0-31), K=128 via 2 x64 steps. S^T: col=l31=qrow,
    //     row(reg i) = key = (i&3)+8*(i>>2)+4*l5.
    f32x16 s;
    #pragma unroll
    for (int i = 0; i < 16; ++i) s[i] = 0.f;
    s = __builtin_amdgcn_mfma_scale_f32_32x32x64_f8f6f4(kv[0], qv[0], s, 0, 0, 0, SCALE1, 0, SCALE1);
    s = __builtin_amdgcn_mfma_scale_f32_32x32x64_f8f6f4(kv[1], qv[1], s, 0, 0, 0, SCALE1, 0, SCALE1);
    // exp/pack tile1 now so only one S tile is ever live (VGPR cap)
    #pragma unroll
    for (int i = 0; i < 16; ++i) {
      float r;
      asm("v_exp_f32 %0, %1" : "=v"(r) : "v"(s[i]));
      s[i] = r;
    }
    #pragma unroll
    for (int i = 0; i < 16; ++i) lacc += s[i];
    uint32_t d0 = pk4_fp8(s[0], s[1], s[2], s[3]);      // keys lo:0-3  hi:4-7
    uint32_t d1 = pk4_fp8(s[4], s[5], s[6], s[7]);      // keys lo:8-11 hi:12-15
    uint32_t d2 = pk4_fp8(s[8], s[9], s[10], s[11]);    // keys lo:16-19 hi:20-23
    uint32_t d3 = pk4_fp8(s[12], s[13], s[14], s[15]);  // keys lo:24-27 hi:28-31

    // (4) QK tile2 (keys 32-63)
    #pragma unroll
    for (int i = 0; i < 16; ++i) s[i] = 0.f;
    s = __builtin_amdgcn_mfma_scale_f32_32x32x64_f8f6f4(kv[2], qv[0], s, 0, 0, 0, SCALE1, 0, SCALE1);
    s = __builtin_amdgcn_mfma_scale_f32_32x32x64_f8f6f4(kv[3], qv[1], s, 0, 0, 0, SCALE1, 0, SCALE1);

    // (5) V dword-half B issue (covered by exp-t2 + swaps + PV front)
    #pragma unroll
    for (int ct = 0; ct < 8; ++ct) vB[ct] = *(const uint4*)(vp + ct * 2048 + 16);

    #pragma unroll
    for (int i = 0; i < 16; ++i) {
      float r;
      asm("v_exp_f32 %0, %1" : "=v"(r) : "v"(s[i]));
      s[i] = r;
    }
    #pragma unroll
    for (int i = 0; i < 16; ++i) lacc += s[i];
    uint32_t e0 = pk4_fp8(s[0], s[1], s[2], s[3]);
    uint32_t e1 = pk4_fp8(s[4], s[5], s[6], s[7]);
    uint32_t e2 = pk4_fp8(s[8], s[9], s[10], s[11]);
    uint32_t e3 = pk4_fp8(s[12], s[13], s[14], s[15]);

    // (6) P^T B-frag (K=64): swap(a=e_i, b=d_i) -> lane<32: a=partner d_i, b=own d_i;
    //     lane>=32: a=own e_i, b=partner e_i. K order = w[2i]=b_i, w[2i+1]=a_i
    //     (lo lanes keys 0-31 = tile1, hi lanes keys 32-63 = tile2). No selects.
    union { uint32_t w[8]; i32x8 v; } pf;
    {
      uint32_t a0 = e0, b0 = d0;
      asm("v_permlane32_swap_b32 %0, %1" : "+v"(a0), "+v"(b0));
      pf.w[0] = b0; pf.w[1] = a0;
      uint32_t a1 = e1, b1 = d1;
      asm("v_permlane32_swap_b32 %0, %1" : "+v"(a1), "+v"(b1));
      pf.w[2] = b1; pf.w[3] = a1;
      uint32_t a2 = e2, b2 = d2;
      asm("v_permlane32_swap_b32 %0, %1" : "+v"(a2), "+v"(b2));
      pf.w[4] = b2; pf.w[5] = a2;
      uint32_t a3 = e3, b3 = d3;
      asm("v_permlane32_swap_b32 %0, %1" : "+v"(a3), "+v"(b3));
      pf.w[6] = b3; pf.w[7] = a3;
    }

    // (7) O^T += V·P^T: 8 x64 MFMAs. D layout identical to before (epilogue unchanged).
    #pragma unroll
    for (int ct = 0; ct < 8; ++ct) {
      union { uint4 u[2]; i32x8 v; } va;
      va.u[0] = vA[ct]; va.u[1] = vB[ct];
      oacc[ct] = __builtin_amdgcn_mfma_scale_f32_32x32x64_f8f6f4(va.v, pf.v, oacc[ct], 0, 0, 0, SCALE1, 0, SCALE1);
    }
  }

  // ---- combine 4 key-quarter waves + epilogue
  float lfin = lacc + __shfl_xor(lacc, 32, 64);

  #pragma unroll
  for (int pq = 0; pq < 4; ++pq) {
    __syncthreads();
    if (pq == 0 && lo) sm.lsum[ks][l31] = lfin;
    if (ks == pq) {
      #pragma unroll
      for (int ct = 0; ct < 8; ++ct) {
        #pragma unroll
        for (int i = 0; i < 16; ++i) {
          int ch = ct * 32 + (i & 3) + 8 * (i >> 2) + 4 * l5;
          if (pq == 0) sm.obuf[ch][l31] = oacc[ct][i];
          else         sm.obuf[ch][l31] += oacc[ct][i];
        }
      }
    }
  }
  __syncthreads();

  const int row = tid & 31;
  const float coef = gamma[0] / (sm.lsum[0][row] + sm.lsum[1][row] +
                                 sm.lsum[2][row] + sm.lsum[3][row]);
  #pragma unroll 4
  for (int t = 0; t < 32; ++t) {
    int ch = (tid >> 5) + t * 8;
    size_t off = ((size_t)(b * Cn + ch)) * Nn + n0 + row;
    out[off] = sm.obuf[ch][row] * coef + 2.0f * x[off];
  }
}

extern "C" void kernel_launch(void* const* d_in, const int* in_sizes, int n_in,
                              void* d_out, int out_size, void* d_ws, size_t ws_size,
                              hipStream_t stream) {
  const float* x     = (const float*)d_in[0];
  const float* Wq    = (const float*)d_in[1];
  const float* bq    = (const float*)d_in[2];
  const float* Wk    = (const float*)d_in[3];
  const float* bk    = (const float*)d_in[4];
  const float* Wv    = (const float*)d_in[5];
  const float* bv    = (const float*)d_in[6];
  const float* gamma = (const float*)d_in[7];
  float* out = (float*)d_out;

  uint8_t* qF = (uint8_t*)d_ws;                       // 2 MB fp8 x64-frag-major
  uint8_t* kF = qF + (2u << 20);                      // 2 MB
  uint8_t* vF = kF + (2u << 20);                      // 4 MB
  unsigned short* wbf = (unsigned short*)(vF + (4u << 20));  // 256 KB bf16 frag-major

  hipLaunchKernelGGL(cvt_weights, dim3(64), dim3(256), 0, stream, Wq, Wk, Wv, wbf);
  hipLaunchKernelGGL(proj_kernel, dim3(128, 4), dim3(256), 0, stream,
                     x, wbf, bq, bk, bv, qF, kF, vF);
  hipLaunchKernelGGL(attn_kernel, dim3(512), dim3(256), 0, stream,
                     qF, kF, vF, x, gamma, out);
}